// Round 5
// baseline (133.900 us; speedup 1.0000x reference)
//
#include <hip/hip_runtime.h>

#define N_INPUTS   1024
#define MAX_HIDDEN 2048
#define MAX_LAYERS 4
#define TOTAL_HIDDEN 8192
#define N_OUTPUTS  512
#define MAX_CONN   2048
#define MAX_OUT_CONN 4096
#define N_VALUES   9216
#define NBLOCKS    256
#define NTHREADS   1024

struct Pack {
    int4 ia, ib, ma, mb;
    float4 wa, wb;
};

__device__ __forceinline__ void load_pack(Pack& p,
        const int* __restrict__ ids, const float* __restrict__ wts,
        const int* __restrict__ cm, size_t c)
{
    p.ia = *reinterpret_cast<const int4*>(ids + c);
    p.ib = *reinterpret_cast<const int4*>(ids + c + 4);
    p.wa = *reinterpret_cast<const float4*>(wts + c);
    p.wb = *reinterpret_cast<const float4*>(wts + c + 4);
    p.ma = *reinterpret_cast<const int4*>(cm + c);
    p.mb = *reinterpret_cast<const int4*>(cm + c + 4);
}

__device__ __forceinline__ float dot_pack(const Pack& p, const float* __restrict__ vals)
{
    float v0 = p.ma.x ? vals[p.ia.x] : 0.f;
    float v1 = p.ma.y ? vals[p.ia.y] : 0.f;
    float v2 = p.ma.z ? vals[p.ia.z] : 0.f;
    float v3 = p.ma.w ? vals[p.ia.w] : 0.f;
    float v4 = p.mb.x ? vals[p.ib.x] : 0.f;
    float v5 = p.mb.y ? vals[p.ib.y] : 0.f;
    float v6 = p.mb.z ? vals[p.ib.z] : 0.f;
    float v7 = p.mb.w ? vals[p.ib.w] : 0.f;
    float s = 0.f;
    s = fmaf(v0, p.wa.x, s);
    s = fmaf(v1, p.wa.y, s);
    s = fmaf(v2, p.wa.z, s);
    s = fmaf(v3, p.wa.w, s);
    s = fmaf(v4, p.wb.x, s);
    s = fmaf(v5, p.wb.y, s);
    s = fmaf(v6, p.wb.z, s);
    s = fmaf(v7, p.wb.w, s);
    return s;
}

__global__ void init_bar_kernel(unsigned* __restrict__ bar) {
    if (threadIdx.x < MAX_LAYERS) bar[threadIdx.x * 32] = 0u;
}

// Compute layer K from packs C0,C1 (already in registers), reduce 2 waves/neuron,
// tanh*amask, publish activation with agent-release store.
#define HIDDEN_COMPUTE(K, C0, C1)                                              \
    {                                                                          \
        float sum = dot_pack(C0, vals) + dot_pack(C1, vals);                   \
        _Pragma("unroll")                                                      \
        for (int off = 32; off > 0; off >>= 1) sum += __shfl_xor(sum, off, 64);\
        if (lane == 0) psum[wave] = sum;                                       \
        __syncthreads();                                                       \
        if (tid < 8) {                                                         \
            const int n = (K) * MAX_HIDDEN + (blockIdx.x << 3) + tid;          \
            float s = psum[tid << 1] + psum[(tid << 1) + 1];                   \
            float a = tanhf(s);                                                \
            if (h_am[n] == 0) a = 0.f;                                         \
            __hip_atomic_store(&gvals[n], a, __ATOMIC_RELEASE,                 \
                               __HIP_MEMORY_SCOPE_AGENT);                      \
        }                                                                      \
        __syncthreads();                                                       \
    }

// Lightweight grid barrier: relaxed arrive, acquire spin (invalidates caches),
// one spinner per block. Next-layer loads issued BEFORE this keep HBM busy.
#define GRID_BARRIER(K)                                                        \
    {                                                                          \
        if (tid == 0) {                                                        \
            __hip_atomic_fetch_add(&bar[(K) * 32], 1u, __ATOMIC_RELAXED,       \
                                   __HIP_MEMORY_SCOPE_AGENT);                  \
            while (__hip_atomic_load(&bar[(K) * 32], __ATOMIC_ACQUIRE,         \
                                     __HIP_MEMORY_SCOPE_AGENT) < NBLOCKS)      \
                __builtin_amdgcn_s_sleep(2);                                   \
        }                                                                      \
        __syncthreads();                                                       \
    }

#define STAGE_ACTS(K)                                                          \
    {                                                                          \
        const float4* g4 = (const float4*)(gvals + (K) * MAX_HIDDEN);          \
        float4* s4 = (float4*)(vals + N_INPUTS + (K) * MAX_HIDDEN);            \
        for (int i = tid; i < (MAX_HIDDEN >> 2); i += NTHREADS) s4[i] = g4[i]; \
        __syncthreads();                                                       \
    }

__global__ void __launch_bounds__(NTHREADS, 4)
fused_net(const float* __restrict__ g_in,
          const int* __restrict__ h_ids, const float* __restrict__ h_w,
          const int* __restrict__ h_cm,  const int* __restrict__ h_am,
          const int* __restrict__ o_ids, const float* __restrict__ o_w,
          const int* __restrict__ o_cm,
          float* __restrict__ out, float* __restrict__ gvals,
          unsigned* __restrict__ bar)
{
    __shared__ float vals[N_VALUES];
    __shared__ float psum[16];

    const int tid  = threadIdx.x;
    const int wave = tid >> 6;
    const int lane = tid & 63;

    // Hidden geometry: 8 neurons/block, 2 waves/neuron, 2 packs/lane.
    const size_t LSTRIDE = (size_t)MAX_HIDDEN * MAX_CONN;   // 4M per layer
    const int hneuron = (blockIdx.x << 3) + (wave >> 1);
    const size_t hbase = (size_t)hneuron * MAX_CONN + ((size_t)(wave & 1) << 10) + (lane << 3);

    // Output geometry: 2 neurons/block, 8 waves/neuron, 1 pack/lane.
    const int oneuron = (blockIdx.x << 1) + (wave >> 3);
    const size_t obase = (size_t)oneuron * MAX_OUT_CONN + ((size_t)(wave & 7) << 9) + (lane << 3);

    Pack P0, P1, Q0, Q1;

    // Prefetch layer 0 stream.
    load_pack(P0, h_ids, h_w, h_cm, hbase);
    load_pack(P1, h_ids, h_w, h_cm, hbase + 512);

    // Stage inputs + zeros into LDS.
    {
        const float4* in4 = reinterpret_cast<const float4*>(g_in);
        float4* s4 = reinterpret_cast<float4*>(vals);
        for (int i = tid; i < (N_VALUES >> 2); i += NTHREADS) {
            float4 v;
            if (i < (N_INPUTS >> 2)) v = in4[i];
            else { v.x = 0.f; v.y = 0.f; v.z = 0.f; v.w = 0.f; }
            s4[i] = v;
        }
    }
    __syncthreads();

    // ---- Layer 0 ----
    HIDDEN_COMPUTE(0, P0, P1);
    load_pack(Q0, h_ids, h_w, h_cm, LSTRIDE + hbase);          // prefetch L1 (covers barrier)
    GRID_BARRIER(0);
    load_pack(Q1, h_ids, h_w, h_cm, LSTRIDE + hbase + 512);
    STAGE_ACTS(0);

    // ---- Layer 1 ----
    HIDDEN_COMPUTE(1, Q0, Q1);
    load_pack(P0, h_ids, h_w, h_cm, 2 * LSTRIDE + hbase);
    GRID_BARRIER(1);
    load_pack(P1, h_ids, h_w, h_cm, 2 * LSTRIDE + hbase + 512);
    STAGE_ACTS(1);

    // ---- Layer 2 ----
    HIDDEN_COMPUTE(2, P0, P1);
    load_pack(Q0, h_ids, h_w, h_cm, 3 * LSTRIDE + hbase);
    GRID_BARRIER(2);
    load_pack(Q1, h_ids, h_w, h_cm, 3 * LSTRIDE + hbase + 512);
    STAGE_ACTS(2);

    // ---- Layer 3 ----
    HIDDEN_COMPUTE(3, Q0, Q1);
    load_pack(P0, o_ids, o_w, o_cm, obase);                    // prefetch output stream
    GRID_BARRIER(3);
    STAGE_ACTS(3);

    // ---- Output layer ----
    {
        float sum = dot_pack(P0, vals);
        #pragma unroll
        for (int off = 32; off > 0; off >>= 1) sum += __shfl_xor(sum, off, 64);
        if (lane == 0) psum[wave] = sum;
        __syncthreads();
        if (tid < 2) {
            float s = 0.f;
            #pragma unroll
            for (int q = 0; q < 8; ++q) s += psum[(tid << 3) + q];
            out[(blockIdx.x << 1) + tid] = s;
        }
    }
}

extern "C" void kernel_launch(void* const* d_in, const int* in_sizes, int n_in,
                              void* d_out, int out_size, void* d_ws, size_t ws_size,
                              hipStream_t stream) {
    const float* input_values = (const float*)d_in[0];
    const int*   h_ids        = (const int*)d_in[1];
    const float* h_w          = (const float*)d_in[2];
    const int*   h_cm         = (const int*)d_in[3];
    const int*   h_am         = (const int*)d_in[4];
    const int*   o_ids        = (const int*)d_in[5];
    const float* o_w          = (const float*)d_in[6];
    const int*   o_cm         = (const int*)d_in[7];
    float*    out   = (float*)d_out;
    float*    gvals = (float*)d_ws;                      // 8192 activations
    unsigned* bar   = (unsigned*)d_ws + TOTAL_HIDDEN;    // 4 counters, 128B apart

    init_bar_kernel<<<1, 64, 0, stream>>>(bar);

    void* args[] = { (void*)&input_values, (void*)&h_ids, (void*)&h_w, (void*)&h_cm,
                     (void*)&h_am, (void*)&o_ids, (void*)&o_w, (void*)&o_cm,
                     (void*)&out, (void*)&gvals, (void*)&bar };

    hipLaunchCooperativeKernel((const void*)fused_net, dim3(NBLOCKS), dim3(NTHREADS),
                               args, 0, stream);
}

// Round 6
// 51.311 us; speedup vs baseline: 2.6096x; 2.6096x over previous
//
#include <hip/hip_runtime.h>

#define N_INPUTS   1024
#define MAX_HIDDEN 2048
#define MAX_LAYERS 4
#define TOTAL_HIDDEN 8192
#define N_OUTPUTS  512
#define MAX_CONN   2048
#define MAX_OUT_CONN 4096
#define N_VALUES   9216

// Stage values prefix into LDS: [0,1024) from inputs, [1024, 1024+staged_hidden)
// from gvals, zeros beyond (future layers must read 0).
__device__ __forceinline__ void stage_values(float* __restrict__ vals,
                                             const float* __restrict__ g_in,
                                             const float* __restrict__ gvals,
                                             int staged_hidden)
{
    const float4* in4 = reinterpret_cast<const float4*>(g_in);
    const float4* gv4 = reinterpret_cast<const float4*>(gvals);
    float4* s4 = reinterpret_cast<float4*>(vals);
    const int nin4 = N_INPUTS >> 2;
    const int pre4 = (N_INPUTS + staged_hidden) >> 2;
    for (int i = threadIdx.x; i < (N_VALUES >> 2); i += blockDim.x) {
        float4 v;
        if (i < nin4)      v = in4[i];
        else if (i < pre4) v = gv4[i - nin4];
        else { v.x = 0.f; v.y = 0.f; v.z = 0.f; v.w = 0.f; }
        s4[i] = v;
    }
}

__device__ __forceinline__ float dot4(int4 ia, float4 wa, int4 ma,
                                      const float* __restrict__ vals)
{
    float s = 0.f;
    s = fmaf(ma.x ? vals[ia.x] : 0.f, wa.x, s);
    s = fmaf(ma.y ? vals[ia.y] : 0.f, wa.y, s);
    s = fmaf(ma.z ? vals[ia.z] : 0.f, wa.z, s);
    s = fmaf(ma.w ? vals[ia.w] : 0.f, wa.w, s);
    return s;
}

// Hidden layer: 2048 neurons x 2048 conns. 512 blocks x 1024 threads (2 blocks/CU).
// 4 neurons/block, 4 waves/neuron (512 conns each), 8 conns/lane as 2 contiguous
// 4-conn groups. Every VMEM instruction covers a contiguous 1KB.
__global__ void __launch_bounds__(1024, 8)
hidden_layer_kernel(const float* __restrict__ g_in,
                    float* __restrict__ gvals,
                    const int* __restrict__ ids,
                    const float* __restrict__ wts,
                    const int* __restrict__ cmask,
                    const int* __restrict__ amask,
                    int row_base)
{
    __shared__ float vals[N_VALUES];
    __shared__ float psum[16];

    const int tid  = threadIdx.x;
    const int wave = tid >> 6;
    const int lane = tid & 63;

    const int neuron = (blockIdx.x << 2) + (wave >> 2);
    const int q      = wave & 3;
    const size_t c0  = (size_t)(row_base + neuron) * MAX_CONN + (q << 9) + (lane << 2);

    // ---- issue stream loads first (in flight during LDS staging) ----
    int4   ia0 = *reinterpret_cast<const int4*>(ids + c0);
    float4 wa0 = *reinterpret_cast<const float4*>(wts + c0);
    int4   ma0 = *reinterpret_cast<const int4*>(cmask + c0);
    int4   ia1 = *reinterpret_cast<const int4*>(ids + c0 + 256);
    float4 wa1 = *reinterpret_cast<const float4*>(wts + c0 + 256);
    int4   ma1 = *reinterpret_cast<const int4*>(cmask + c0 + 256);

    stage_values(vals, g_in, gvals, row_base);
    __syncthreads();

    float sum = dot4(ia0, wa0, ma0, vals) + dot4(ia1, wa1, ma1, vals);

    #pragma unroll
    for (int off = 32; off > 0; off >>= 1)
        sum += __shfl_xor(sum, off, 64);

    if (lane == 0) psum[wave] = sum;
    __syncthreads();

    if (tid < 4) {
        const int n = (blockIdx.x << 2) + tid;
        float s = psum[(tid << 2)] + psum[(tid << 2) + 1]
                + psum[(tid << 2) + 2] + psum[(tid << 2) + 3];
        float a = tanhf(s);
        if (amask[row_base + n] == 0) a = 0.f;
        gvals[row_base + n] = a;
    }
}

// Output layer: 512 neurons x 4096 conns. 512 blocks x 1024 threads.
// 1 neuron/block, 16 waves, 4 conns/lane (1 contiguous group).
__global__ void __launch_bounds__(1024, 8)
output_layer_kernel(const float* __restrict__ g_in,
                    const float* __restrict__ gvals,
                    const int* __restrict__ ids,
                    const float* __restrict__ wts,
                    const int* __restrict__ cmask,
                    float* __restrict__ out)
{
    __shared__ float vals[N_VALUES];
    __shared__ float psum[16];

    const int tid  = threadIdx.x;
    const int wave = tid >> 6;
    const int lane = tid & 63;

    const size_t c0 = (size_t)blockIdx.x * MAX_OUT_CONN + (wave << 8) + (lane << 2);

    int4   ia = *reinterpret_cast<const int4*>(ids + c0);
    float4 wa = *reinterpret_cast<const float4*>(wts + c0);
    int4   ma = *reinterpret_cast<const int4*>(cmask + c0);

    stage_values(vals, g_in, gvals, TOTAL_HIDDEN);
    __syncthreads();

    float sum = dot4(ia, wa, ma, vals);

    #pragma unroll
    for (int off = 32; off > 0; off >>= 1)
        sum += __shfl_xor(sum, off, 64);

    if (lane == 0) psum[wave] = sum;
    __syncthreads();

    if (tid == 0) {
        float s = 0.f;
        #pragma unroll
        for (int q = 0; q < 16; ++q) s += psum[q];
        out[blockIdx.x] = s;
    }
}

extern "C" void kernel_launch(void* const* d_in, const int* in_sizes, int n_in,
                              void* d_out, int out_size, void* d_ws, size_t ws_size,
                              hipStream_t stream) {
    const float* input_values = (const float*)d_in[0];
    const int*   h_ids        = (const int*)d_in[1];
    const float* h_w          = (const float*)d_in[2];
    const int*   h_cm         = (const int*)d_in[3];
    const int*   h_am         = (const int*)d_in[4];
    const int*   o_ids        = (const int*)d_in[5];
    const float* o_w          = (const float*)d_in[6];
    const int*   o_cm         = (const int*)d_in[7];
    float* out   = (float*)d_out;
    float* gvals = (float*)d_ws;   // hidden activations: 8192 floats

    for (int k = 0; k < MAX_LAYERS; ++k) {
        hidden_layer_kernel<<<512, 1024, 0, stream>>>(
            input_values, gvals, h_ids, h_w, h_cm, h_am, k * MAX_HIDDEN);
    }

    output_layer_kernel<<<512, 1024, 0, stream>>>(
        input_values, gvals, o_ids, o_w, o_cm, out);
}